// Round 9
// baseline (211.657 us; speedup 1.0000x reference)
//
#include <hip/hip_runtime.h>
#include <math.h>

#define NN 2048
#define DD 512
#define HH 8
#define EE 64

typedef unsigned short u16;
typedef __attribute__((ext_vector_type(8))) short bf16x8;
typedef __attribute__((ext_vector_type(4))) float f32x4;

#define MFMA(a,b,c) __builtin_amdgcn_mfma_f32_16x16x32_bf16((a),(b),(c),0,0,0)

__device__ __forceinline__ float fexp2(float x){
#if __has_builtin(__builtin_amdgcn_exp2f)
  return __builtin_amdgcn_exp2f(x);
#else
  return exp2f(x);
#endif
}

// round-to-nearest-even fp32 -> bf16 (finite inputs only)
__device__ __forceinline__ unsigned rnd1(float x){
  unsigned u = __float_as_uint(x);
  return (u + 0x7fffu + ((u >> 16) & 1u)) >> 16;
}
__device__ __forceinline__ unsigned pk2(float a, float b){
  return rnd1(a) | (rnd1(b) << 16);
}
// truncation pack (P only: small negative bias, in error budget)
__device__ __forceinline__ unsigned tpk2(float a, float b){
  return (__float_as_uint(a) >> 16) | (__float_as_uint(b) & 0xffff0000u);
}
union I4V { int4 i; bf16x8 v; };
__device__ __forceinline__ bf16x8 ld_frag(const u16* p){
  I4V u; u.i = *(const int4*)p; return u.v;
}
__device__ __forceinline__ bf16x8 mk_frag(int a, int b, int c, int d){
  I4V u; u.i = make_int4(a,b,c,d); return u.v;
}

// ===========================================================================
// Packed fragment layouts (lane = q*16+jl; chunk = 8 k-contiguous bf16 = 16B):
//  wpk [p][h][kc16][es4][lane][8] : W_p[h][e=es*16+jl][d=kc*32+q*8+jj]  (Wq scaled)
//  wopk[ot8][kc16][os4][lane][8]  : Wo[h=k>>6][o=ot*64+os*16+jl][e=k&63], k=kc*32+q*8+jj
//  xpk [p][b][ng128][kc16][lane][8] : X_p[b][n=ng*16+jl][d=kc*32+q*8+jj]
//  Qpk/Kpk[bh][ng128][kh2][lane][8] : Q[bh][n=ng*16+jl][e=kh*32+q*8+jj]
//  Vpk [bh][jt32][jc2][es4][lane][8]: V[bh][j=jt*64+jc*32+q*8+jj][e=es*16+jl]
//  Rpk [rg512][kc16][lane][8]       : rep[r=rg*16+jl][k=h*64+e=kc*32+q*8+jj]
// ===========================================================================

// ---------------------------------------------------------------------------
// Pack kernel: z<12 = x pack (fp32 -> bf16 B-frags via LDS transpose),
// z in {12,13} = weight pre-convert+pack.  grid (32, 8, 14), 256 thr.
// ---------------------------------------------------------------------------
__global__ __launch_bounds__(256) void pack_kernel(
    const float* __restrict__ x1, const float* __restrict__ x2,
    const float* __restrict__ vin,
    const float* __restrict__ Wq, const float* __restrict__ Wk,
    const float* __restrict__ Wv, const float* __restrict__ Wo,
    u16* __restrict__ xpk, u16* __restrict__ wpk, u16* __restrict__ wopk)
{
  __shared__ float lds[64][68];
  const int z = blockIdx.z;
  const int t = threadIdx.x;

  if (z < 12) {
    const int nt = blockIdx.x, dt = blockIdx.y, pb = z;
    const int p = pb >> 2, b = pb & 3;
    const float* X = (p == 0) ? x2 : (p == 1) ? x1 : vin;

    {
      const int r = t >> 2, c0 = (t & 3) * 16;
      const float* src = X + ((size_t)b * NN + nt * 64 + r) * DD + dt * 64 + c0;
      float4 f0 = ((const float4*)src)[0];
      float4 f1 = ((const float4*)src)[1];
      float4 f2 = ((const float4*)src)[2];
      float4 f3 = ((const float4*)src)[3];
      *(float4*)&lds[r][c0]      = f0;
      *(float4*)&lds[r][c0 + 4]  = f1;
      *(float4*)&lds[r][c0 + 8]  = f2;
      *(float4*)&lds[r][c0 + 12] = f3;
    }
    __syncthreads();

    const int lane = t & 63, w = t >> 6, jl = lane & 15, q = lane >> 4;
    #pragma unroll
    for (int kcl = 0; kcl < 2; ++kcl) {
      float4 fa = *(const float4*)&lds[w * 16 + jl][kcl * 32 + q * 8];
      float4 fb = *(const float4*)&lds[w * 16 + jl][kcl * 32 + q * 8 + 4];
      int4 pk = make_int4(pk2(fa.x, fa.y), pk2(fa.z, fa.w),
                          pk2(fb.x, fb.y), pk2(fb.z, fb.w));
      const int ng = nt * 4 + w, kc = dt * 2 + kcl;
      *(int4*)&xpk[((((size_t)pb * 128 + ng) * 16 + kc) * 64 + lane) * 8] = pk;
    }
  } else {
    const int zi = (z - 12) * 256 + blockIdx.y * 32 + blockIdx.x;  // 0..511
    const int gid = zi * 256 + t;                                  // 0..131071
    const int seg = gid >> 15, tid = gid & 32767;
    const int lane = tid & 63, jl = lane & 15, q = lane >> 4;
    const int es = (tid >> 6) & 3, kc = (tid >> 8) & 15, hh = tid >> 12;

    if (seg < 3) {
      const float* Wsrc = (seg == 0) ? Wq : (seg == 1) ? Wk : Wv;
      const float s = (seg == 0) ? 0.18033688011112042f : 1.0f;  // log2e/sqrt(E)
      const float* src = Wsrc + ((size_t)hh * 64 + es * 16 + jl) * DD + kc * 32 + q * 8;
      float4 fa = *(const float4*)src;
      float4 fb = *(const float4*)(src + 4);
      int4 pk = make_int4(pk2(fa.x*s, fa.y*s), pk2(fa.z*s, fa.w*s),
                          pk2(fb.x*s, fb.y*s), pk2(fb.z*s, fb.w*s));
      *(int4*)&wpk[(size_t)(((seg*8 + hh)*16 + kc)*4 + es)*512 + lane*8] = pk;
    } else {
      const int k = kc * 32 + q * 8;           // h = k>>6, e = k&63 (8 contiguous)
      const float* src = Wo + ((size_t)(k >> 6) * DD + hh * 64 + es * 16 + jl) * EE + (k & 63);
      float4 fa = *(const float4*)src;
      float4 fb = *(const float4*)(src + 4);
      int4 pk = make_int4(pk2(fa.x, fa.y), pk2(fa.z, fa.w),
                          pk2(fb.x, fb.y), pk2(fb.z, fb.w));
      *(int4*)&wopk[(size_t)(((hh*16 + kc)*4 + es)*512) + lane*8] = pk;
    }
  }
}

// ---------------------------------------------------------------------------
// Q/K/V projection: fully packed operands, no LDS.  grid (128: b*32+nt, 24: p*8+h).
// (round-5 form, known good)
// ---------------------------------------------------------------------------
__global__ __launch_bounds__(256) void qkvproj_kernel(
    const u16* __restrict__ xpk, const u16* __restrict__ wpk,
    u16* __restrict__ Qpk, u16* __restrict__ Kpk, u16* __restrict__ Vpk)
{
  const int t = threadIdx.x, w = t >> 6, lane = t & 63;
  const int jl = lane & 15, q = lane >> 4;
  const int bn = blockIdx.x, ph = blockIdx.y;
  const int b = bn >> 5, nt = bn & 31, p = ph >> 3, h = ph & 7;

  const u16* xb = xpk + (((size_t)(p * 4 + b) * 128 + nt * 4 + w) * 16) * 512;
  const u16* wb = wpk + (size_t)ph * 32768;

  f32x4 acc[4];
  #pragma unroll
  for (int i = 0; i < 4; ++i) acc[i] = (f32x4){0.f,0.f,0.f,0.f};

  #pragma unroll 4
  for (int kc = 0; kc < 16; ++kc) {
    bf16x8 xf = ld_frag(xb + kc * 512 + lane * 8);
    #pragma unroll
    for (int es = 0; es < 4; ++es) {
      bf16x8 wf = ld_frag(wb + (size_t)(kc * 4 + es) * 512 + lane * 8);
      acc[es] = MFMA(wf, xf, acc[es]);
    }
  }

  const int bh = b * 8 + h;
  if (p < 2) {
    u16* O = (p ? Kpk : Qpk) + (size_t)bh * 131072;
    const int ng = nt * 4 + w;
    #pragma unroll
    for (int es = 0; es < 4; ++es) {
      const int kh = es >> 1, qp = (es & 1) * 2 + (q >> 1), off = (q & 1) * 4;
      *(uint2*)&O[(size_t)((ng * 2 + kh) * 64 + qp * 16 + jl) * 8 + off] =
          make_uint2(pk2(acc[es][0], acc[es][1]), pk2(acc[es][2], acc[es][3]));
    }
  } else {
    u16* O = Vpk + (size_t)bh * 131072 + nt * 4096;
    const int jc = w >> 1, qp = (w & 1) * 2 + (jl >> 3), jj = jl & 7;
    #pragma unroll
    for (int es = 0; es < 4; ++es)
      #pragma unroll
      for (int r = 0; r < 4; ++r)
        O[(size_t)((jc * 4 + es) * 64 + qp * 16 + q * 4 + r) * 8 + jj] =
            (u16)rnd1(acc[es][r]);
  }
}

// ---------------------------------------------------------------------------
// Attention v2 — i-split waves.  Block = (bh, 64 i-rows); wave w owns 16
// i-rows (ig = itile*4+w) and iterates ALL 32 j-tiles.  No cross-wave
// reduction -> zero __syncthreads, no combine slabs.  Per-wave registers:
// qf 8 + kf 32 + vf 32 + acc 16 AGPR ~= 112 -> 4 waves/SIMD.
// Keeps round-8 pipeline: V loads first (hidden by S phase), K[jt+1]
// reloaded in place after last use (hidden by PV phase).
// P round-trip through per-wave-private LDS (16x64 tile, stride 72).
// ---------------------------------------------------------------------------
__global__ __launch_bounds__(256) void attn_kernel(
    const u16* __restrict__ Qpk, const u16* __restrict__ Kpk,
    const u16* __restrict__ Vpk, u16* __restrict__ Rpk)
{
  __shared__ short P[4][16][72];   // per-wave [i][j], 144 B rows

  const int tid = threadIdx.x, w = tid >> 6, lane = tid & 63;
  const int jl = lane & 15, q = lane >> 4;
  const int bx = blockIdx.x;
  const int itile = bx >> 5;        // bh fast: XCD sees fixed bh mod 8 -> L2 locality
  const int bh = bx & 31;
  const int b = bh >> 3, h = bh & 7;
  const int ig = itile * 4 + w;     // this wave's 16-row i-group (0..127)

  // Q fragments: 2 frags = 8 VGPRs, persistent
  bf16x8 qf[2];
  #pragma unroll
  for (int kh = 0; kh < 2; ++kh)
    qf[kh] = ld_frag(Qpk + (((size_t)bh * 128 + ig) * 2 + kh) * 512 + lane * 8);

  const u16* Kp = Kpk + (size_t)bh * 131072;
  const u16* Vp = Vpk + (size_t)bh * 131072;

  char* pw = (char*)&P[0][0][0] + w * 2304 + jl * 144 + q * 8;        // write base
  const char* pr = (const char*)&P[0][0][0] + w * 2304 + jl * 144 + q * 16; // read base

  f32x4 acc[4];
  #pragma unroll
  for (int es = 0; es < 4; ++es) acc[es] = (f32x4){0.f,0.f,0.f,0.f};
  float lac = 0.f;

  // preload K[0]
  bf16x8 kf[4][2];
  #pragma unroll
  for (int jm = 0; jm < 4; ++jm) {
    kf[jm][0] = ld_frag(Kp + jm * 1024 + lane * 8);
    kf[jm][1] = ld_frag(Kp + jm * 1024 + 512 + lane * 8);
  }

  for (int jt = 0; jt < 32; ++jt) {
    // ---- V[jt] loads first: consumed after S phase ----
    const u16* Vb = Vp + jt * 4096;
    bf16x8 vf[4][2];
    #pragma unroll
    for (int es = 0; es < 4; ++es) {
      vf[es][0] = ld_frag(Vb + es * 512 + lane * 8);
      vf[es][1] = ld_frag(Vb + 2048 + es * 512 + lane * 8);
    }
    // ---- S^T tile (64j x 16i): 4 jm sub-tiles; exp2; P -> LDS ----
    #pragma unroll
    for (int jm = 0; jm < 4; ++jm) {
      f32x4 c = (f32x4){0.f,0.f,0.f,0.f};
      c = MFMA(kf[jm][0], qf[0], c);
      c = MFMA(kf[jm][1], qf[1], c);
      float e0 = fexp2(c[0]), e1 = fexp2(c[1]);
      float e2 = fexp2(c[2]), e3 = fexp2(c[3]);
      lac += (e0 + e1) + (e2 + e3);
      int2 pv; pv.x = tpk2(e0, e1); pv.y = tpk2(e2, e3);
      *(int2*)(pw + jm * 32) = pv;   // row i=jl, cols j=jm*16+q*4..+3
    }
    // ---- K[jt+1] in-place reload (WAR; latency hidden by PV) ----
    {
      const u16* Kn = Kp + ((jt + 1) & 31) * 4096;
      #pragma unroll
      for (int jm = 0; jm < 4; ++jm) {
        kf[jm][0] = ld_frag(Kn + jm * 1024 + lane * 8);
        kf[jm][1] = ld_frag(Kn + jm * 1024 + 512 + lane * 8);
      }
    }
    // ---- PV: acc += P * V  (P as A-frags from LDS, wave-private) ----
    {
      I4V u0, u1;
      u0.i.x = *(const int*)(pr);       u0.i.y = *(const int*)(pr + 4);
      u0.i.z = *(const int*)(pr + 8);   u0.i.w = *(const int*)(pr + 12);
      u1.i.x = *(const int*)(pr + 64);  u1.i.y = *(const int*)(pr + 68);
      u1.i.z = *(const int*)(pr + 72);  u1.i.w = *(const int*)(pr + 76);
      bf16x8 p0 = u0.v, p1 = u1.v;
      #pragma unroll
      for (int es = 0; es < 4; ++es) {
        acc[es] = MFMA(p0, vf[es][0], acc[es]);
        acc[es] = MFMA(p1, vf[es][1], acc[es]);
      }
    }
  }

  // ---- normalize: row-sum l lives at i=jl; acc rows are i=q*4+r ----
  float lv = lac;
  lv += __shfl_xor(lv, 16, 64);
  lv += __shfl_xor(lv, 32, 64);
  const float il = 1.0f / lv;        // reciprocal for row i = jl
  float ilr[4];
  #pragma unroll
  for (int r = 0; r < 4; ++r)
    ilr[r] = __shfl(il, q * 4 + r, 64);   // reciprocal for row i = q*4+r

  // ---- store rep rows (ig*16 + q*4+r) into packed Rpk ----
  const int rg = b * 128 + ig;
  #pragma unroll
  for (int es = 0; es < 4; ++es) {
    const int kk = es * 16 + jl;          // k-local = e within head
    const int kc = h * 2 + (kk >> 5), qp = (kk >> 3) & 3, jj = jl & 7;
    #pragma unroll
    for (int r = 0; r < 4; ++r) {
      Rpk[((size_t)rg * 16 + kc) * 512 + (size_t)(qp * 16 + q * 4 + r) * 8 + jj] =
          (u16)rnd1(acc[es][r] * ilr[r]);
    }
  }
}

// ---------------------------------------------------------------------------
// Output projection: fully packed, no LDS.  grid (128 rt, 8 ot) (round-5 form).
// ---------------------------------------------------------------------------
__global__ __launch_bounds__(256) void outproj_kernel(
    const u16* __restrict__ Rpk, const u16* __restrict__ wopk,
    float* __restrict__ out)
{
  const int t = threadIdx.x, w = t >> 6, lane = t & 63;
  const int jl = lane & 15, q = lane >> 4;
  const int rt = blockIdx.x, ot = blockIdx.y;
  const int rg = rt * 4 + w;

  f32x4 acc[4];
  #pragma unroll
  for (int i = 0; i < 4; ++i) acc[i] = (f32x4){0.f,0.f,0.f,0.f};

  #pragma unroll 4
  for (int kc = 0; kc < 16; ++kc) {
    bf16x8 bf = ld_frag(Rpk + ((size_t)rg * 16 + kc) * 512 + lane * 8);
    #pragma unroll
    for (int os = 0; os < 4; ++os) {
      bf16x8 wf = ld_frag(wopk + (size_t)((ot * 16 + kc) * 4 + os) * 512 + lane * 8);
      acc[os] = MFMA(wf, bf, acc[os]);
    }
  }

  #pragma unroll
  for (int os = 0; os < 4; ++os) {
    float4 o4 = make_float4(acc[os][0], acc[os][1], acc[os][2], acc[os][3]);
    *(float4*)&out[(size_t)(rt * 64 + w * 16 + jl) * DD + ot * 64 + os * 16 + q * 4] = o4;
  }
}

// ---------------------------------------------------------------------------
extern "C" void kernel_launch(void* const* d_in, const int* in_sizes, int n_in,
                              void* d_out, int out_size, void* d_ws, size_t ws_size,
                              hipStream_t stream)
{
  const float* x1 = (const float*)d_in[0];
  const float* x2 = (const float*)d_in[1];
  const float* vv = (const float*)d_in[2];
  const float* Wq = (const float*)d_in[3];
  const float* Wk = (const float*)d_in[4];
  const float* Wv = (const float*)d_in[5];
  const float* Wo = (const float*)d_in[6];
  float* out = (float*)d_out;

  char* W = (char*)d_ws;                        // ~58 MB total
  u16* wpk  = (u16*)(W);                        // 1.5 MB
  u16* wopk = (u16*)(W + 1572864);              // 0.5 MB
  u16* xpk  = (u16*)(W + 2097152);              // 24 MB
  u16* Qpk  = (u16*)(W + 27262976);             // 8 MB
  u16* Kpk  = (u16*)(W + 35651584);             // 8 MB
  u16* Vpk  = (u16*)(W + 44040192);             // 8 MB
  u16* Rpk  = (u16*)(W + 52428800);             // 8 MB

  pack_kernel   <<<dim3(32, 8, 14), 256, 0, stream>>>(x1, x2, vv, Wq, Wk, Wv, Wo,
                                                      xpk, wpk, wopk);
  qkvproj_kernel<<<dim3(128, 24), 256, 0, stream>>>(xpk, wpk, Qpk, Kpk, Vpk);
  attn_kernel   <<<dim3(1024), 256, 0, stream>>>(Qpk, Kpk, Vpk, Rpk);
  outproj_kernel<<<dim3(128, 8), 256, 0, stream>>>(Rpk, wopk, out);
}